// Round 15
// baseline (131.597 us; speedup 1.0000x reference)
//
#include <hip/hip_runtime.h>
#include <hip/hip_bf16.h>

// ParallelMHA: B=2, N=2048, D=1024, H=16, HD=64. fp32 in/out, bf16 MFMA compute.
// Pipeline: convert (1 launch) -> QKV GEMM (gload_lds; Q*log2e/8; K,V lane-linear
//           fragment layout) -> flash attn (fixed-max, XCD-pinned, swapped-QK,
//           zero-shuffle P, QBLK=64/wave, block-shared LDS K/V dbuf) -> O GEMM
// R11-R14 post-mortem: per-wave-tile cost ~3000cyc invariant under occupancy/
// balance/VALU/sharing changes; only per-wave-load-per-q-row reduction (R10) ever
// helped. R15: double q-rows per wave (32->64, mf=0..3) => half the tiles system-
// wide at ~same per-tile cost. 256 blocks x 4 waves, launch_bounds(256,1).

typedef __bf16 bf16;
typedef __bf16 bf16x2 __attribute__((ext_vector_type(2)));
typedef __bf16 bf16x4 __attribute__((ext_vector_type(4)));
typedef __bf16 bf16x8 __attribute__((ext_vector_type(8)));
typedef float f32x4 __attribute__((ext_vector_type(4)));
typedef unsigned int u32x4 __attribute__((ext_vector_type(4)));

__device__ __forceinline__ f32x4 mfma16(bf16x8 a, bf16x8 b, f32x4 c) {
    return __builtin_amdgcn_mfma_f32_16x16x32_bf16(a, b, c, 0, 0, 0);
}

__device__ __forceinline__ void gload16(const bf16* g, bf16* l) {
    __builtin_amdgcn_global_load_lds(
        (const __attribute__((address_space(1))) unsigned int*)g,
        (__attribute__((address_space(3))) unsigned int*)l, 16, 0, 0);
}

__device__ __forceinline__ unsigned pk2(float a, float b) {
    bf16x2 v;
    v[0] = (bf16)a;
    v[1] = (bf16)b;
    return __builtin_bit_cast(unsigned, v);
}

// ---------------- fp32 -> bf16 convert (x + 4 weights, one launch) ----------------
__global__ __launch_bounds__(256) void conv_kernel(
    const float* __restrict__ x, const float* __restrict__ w0,
    const float* __restrict__ w1, const float* __restrict__ w2,
    const float* __restrict__ w3, bf16* __restrict__ xb,
    bf16* __restrict__ o0, bf16* __restrict__ o1,
    bf16* __restrict__ o2, bf16* __restrict__ o3) {
    int blk = blockIdx.x;
    const float* in;
    bf16* out;
    int base;
    if (blk < 4096) {
        in = x; out = xb; base = blk;
    } else {
        int sel = (blk - 4096) >> 10;
        in = sel == 0 ? w0 : sel == 1 ? w1 : sel == 2 ? w2 : w3;
        out = sel == 0 ? o0 : sel == 1 ? o1 : sel == 2 ? o2 : o3;
        base = (blk - 4096) & 1023;
    }
    int i = (base * 256 + threadIdx.x) * 4;
    float4 v = *(const float4*)&in[i];
    bf16x4 o;
    o.x = (bf16)v.x; o.y = (bf16)v.y; o.z = (bf16)v.z; o.w = (bf16)v.w;
    *(bf16x4*)&out[i] = o;
}

// ---------------- 128x128 bf16 GEMM, global_load_lds staging -------
// MODE 0: bf16 row-major *scale. MODE 1: f32 out + bias.
// MODE 2: V lane-linear fragment (key-permuted). MODE 3: K lane-linear fragment.
template <int MODE>
__device__ __forceinline__ void gemm_body(const bf16* __restrict__ A,
                                          const bf16* __restrict__ B,
                                          bf16* __restrict__ Cb,
                                          float* __restrict__ Cf,
                                          const float* __restrict__ bias,
                                          float scale, int N, int K, int row0, int col0) {
    __shared__ alignas(16) bf16 sA[128 * 32];
    __shared__ alignas(16) bf16 sB[128 * 32];
    const int tid  = threadIdx.x;
    const int lane = tid & 63;
    const int wave = tid >> 6;
    const int wrow = (wave >> 1) * 64;
    const int wcol = (wave & 1) * 64;
    const int la = lane & 15, lb = lane >> 4;

    const f32x4 fzero = {0.f, 0.f, 0.f, 0.f};
    f32x4 acc[4][4];
#pragma unroll
    for (int m = 0; m < 4; ++m)
#pragma unroll
        for (int n = 0; n < 4; ++n) acc[m][n] = fzero;

    for (int k0 = 0; k0 < K; k0 += 32) {
#pragma unroll
        for (int i = 0; i < 2; ++i) {
            int idx = i * 256 + tid;
            int r = idx >> 2, s = idx & 3;
            gload16(&A[(size_t)(row0 + r) * K + k0 + s * 8], &sA[idx * 8]);
            gload16(&B[(size_t)(col0 + r) * K + k0 + s * 8], &sB[idx * 8]);
        }
        __syncthreads();
        bf16x8 af[4], bfv[4];
#pragma unroll
        for (int m = 0; m < 4; ++m)
            af[m] = *(const bf16x8*)&sA[(wrow + m * 16 + la) * 32 + lb * 8];
#pragma unroll
        for (int n = 0; n < 4; ++n)
            bfv[n] = *(const bf16x8*)&sB[(wcol + n * 16 + la) * 32 + lb * 8];
#pragma unroll
        for (int m = 0; m < 4; ++m)
#pragma unroll
            for (int n = 0; n < 4; ++n)
                acc[m][n] = mfma16(af[m], bfv[n], acc[m][n]);
        __syncthreads();
    }
#pragma unroll
    for (int m = 0; m < 4; ++m)
#pragma unroll
        for (int n = 0; n < 4; ++n) {
            int col = col0 + wcol + n * 16 + la;
            if (MODE == 2) {
                int hh = col >> 6, hd = col & 63;
                int hc = hd >> 4, lav = hd & 15;
                int sp = row0 + wrow + m * 16 + lb * 4;
                int ktile = sp >> 6, k = sp & 63;
                int c = k >> 4, g = (k >> 2) & 3;
                size_t addr = (size_t)(ktile * 16 + hh) * 4096 +
                              (size_t)((hc * 2 + (c >> 1)) * 512 +
                                       (lav + g * 16) * 8 + (c & 1) * 4);
                bf16x4 o4;
#pragma unroll
                for (int r = 0; r < 4; ++r) o4[r] = (bf16)acc[m][n][r];
                *(bf16x4*)&Cb[addr] = o4;
            } else if (MODE == 3) {
                int hh = col >> 6, hd = col & 63;
#pragma unroll
                for (int r = 0; r < 4; ++r) {
                    int row = row0 + wrow + m * 16 + lb * 4 + r;
                    int ktile = row >> 6, key = row & 63;
                    size_t addr = (size_t)(ktile * 16 + hh) * 4096 +
                                  (size_t)(((key >> 4) * 2 + (hd >> 5)) * 512 +
                                           ((key & 15) + ((hd >> 3) & 3) * 16) * 8 +
                                           (hd & 7));
                    Cb[addr] = (bf16)acc[m][n][r];
                }
            } else {
#pragma unroll
                for (int r = 0; r < 4; ++r) {
                    int row = row0 + wrow + m * 16 + lb * 4 + r;
                    if (MODE == 1)
                        Cf[(size_t)row * N + col] = acc[m][n][r] + bias[col];
                    else
                        Cb[(size_t)row * N + col] = (bf16)(acc[m][n][r] * scale);
                }
            }
        }
}

__global__ __launch_bounds__(256) void gemm_qkv_kernel(
    const bf16* __restrict__ xb, const bf16* __restrict__ wq,
    const bf16* __restrict__ wk, const bf16* __restrict__ wv,
    bf16* __restrict__ Q, bf16* __restrict__ Kf, bf16* __restrict__ Vf) {
    int z = blockIdx.z;
    if (z == 2) {
        gemm_body<2>(xb, wv, Vf, nullptr, nullptr, 1.f, 1024, 1024,
                     blockIdx.x * 128, blockIdx.y * 128);
    } else if (z == 1) {
        gemm_body<3>(xb, wk, Kf, nullptr, nullptr, 1.f, 1024, 1024,
                     blockIdx.x * 128, blockIdx.y * 128);
    } else {
        gemm_body<0>(xb, wq, Q, nullptr, nullptr, 0.1803368801111204f, 1024, 1024,
                     blockIdx.x * 128, blockIdx.y * 128);
    }
}

__global__ __launch_bounds__(256) void gemm_out_kernel(
    const bf16* __restrict__ att, const bf16* __restrict__ wo,
    float* __restrict__ out, const float* __restrict__ bias) {
    gemm_body<1>(att, wo, nullptr, out, bias, 1.f, 1024, 1024,
                 blockIdx.x * 128, blockIdx.y * 128);
}

// ---------------- flash attention: QBLK=64/wave, block-shared LDS K/V ----------------
// 256 blocks x 4 waves; block = (b,h) x 256 q-rows (qb = bid>>5); wave owns 64 rows
// (mf=0..3). K/V tiles staged once per block into LDS (dbuf 32KB), barrier-uniform
// trip count ntmax = 4*qb+4. p = exp2(s - 10*log2e) fixed-max.
__global__ __launch_bounds__(256, 1) void attn_kernel(
    const bf16* __restrict__ Q, const bf16* __restrict__ Kf,
    const bf16* __restrict__ Vf, bf16* __restrict__ O) {
    __shared__ alignas(16) char smem[32768];  // [2][ K 8KB | V 8KB ]
    const int lane = threadIdx.x & 63;
    const int wave = threadIdx.x >> 6;
    const int bid = blockIdx.x;                       // 0..255
    const int bh = (bid & 7) * 4 + ((bid >> 3) & 3);  // XCD-pinned (b,h)
    const int qb = bid >> 5;                          // 0..7 : 256-row q-block
    const int h = bh & 15;
    const int b = bh >> 4;
    const int q0w = qb * 256 + wave * 64;
    const int rowbase = b * 2048;
    const int la = lane & 15, lb = lane >> 4;
    const f32x4 fzero = {0.f, 0.f, 0.f, 0.f};
    const float C = 14.426950408889634f;  // 10 * log2(e)
    const int colbase = h * 64;
    const size_t TSTRIDE = 16 * 4096;

    const bf16* kg = Kf + ((size_t)(b * 32) * 16 + h) * 4096 + lane * 8;
    const bf16* vg = Vf + ((size_t)(b * 32) * 16 + h) * 4096 + lane * 8;

    // Q fragments: 4 x 16 rows (mf), k-dim 64 (2 chunks)
    bf16x8 aq[4][2];
#pragma unroll
    for (int mf = 0; mf < 4; ++mf) {
        const bf16* qp = &Q[(size_t)(rowbase + q0w + mf * 16 + la) * 1024 + colbase];
#pragma unroll
        for (int kc = 0; kc < 2; ++kc) aq[mf][kc] = *(const bf16x8*)(qp + kc * 32 + lb * 8);
    }

    bf16x8 bones;
#pragma unroll
    for (int j = 0; j < 8; ++j) bones[j] = (bf16)1.0f;

    f32x4 o[4][4], lacc[4];
#pragma unroll
    for (int mf = 0; mf < 4; ++mf) {
        lacc[mf] = fzero;
#pragma unroll
        for (int hc = 0; hc < 4; ++hc) o[mf][hc] = fzero;
    }

    const int nt = 4 * qb + wave + 1;   // this wave's causal trip count
    const int ntmax = 4 * qb + 4;       // block-uniform

    auto STAGE = [&](int tile, int cur) {
        const bf16* ks = kg + (size_t)tile * TSTRIDE;
        const bf16* vs = vg + (size_t)tile * TSTRIDE;
        char* dst = smem + cur * 16384;
#pragma unroll
        for (int i = 0; i < 2; ++i) {
            int f = wave + i * 4;
            gload16(ks + f * 512, (bf16*)(dst + f * 1024));
            gload16(vs + f * 512, (bf16*)(dst + 8192 + f * 1024));
        }
    };

    STAGE(0, 0);
    __syncthreads();

    int cur = 0;
    for (int t = 0; t < ntmax; ++t) {
        if (t + 1 < ntmax) STAGE(t + 1, cur ^ 1);
        if (t < nt) {
            const char* kbuf = smem + cur * 16384;
            const char* vbuf = kbuf + 8192;
            // per-mf QK + softmax -> pa
            bf16x8 pa[4][2];
            __builtin_amdgcn_s_setprio(1);
#pragma unroll
            for (int mf = 0; mf < 4; ++mf) {
                f32x4 s[4];
#pragma unroll
                for (int ck = 0; ck < 4; ++ck) s[ck] = fzero;
#pragma unroll
                for (int ck = 0; ck < 4; ++ck) {
                    bf16x8 k0 = *(const bf16x8*)(kbuf + (ck * 2 + 0) * 1024 + lane * 16);
                    bf16x8 k1 = *(const bf16x8*)(kbuf + (ck * 2 + 1) * 1024 + lane * 16);
                    s[ck] = mfma16(k0, aq[mf][0], s[ck]);
                    s[ck] = mfma16(k1, aq[mf][1], s[ck]);
                }
                if (t == nt - 1) {
                    const int k0r = t * 64;
                    int qrow = q0w + mf * 16 + la;
#pragma unroll
                    for (int ck = 0; ck < 4; ++ck)
#pragma unroll
                        for (int r = 0; r < 4; ++r) {
                            int key = k0r + ck * 16 + lb * 4 + r;
                            if (key > qrow) s[ck][r] = -1e30f;
                        }
                }
                unsigned pk[4][2];
#pragma unroll
                for (int ck = 0; ck < 4; ++ck) {
                    float p0 = __builtin_amdgcn_exp2f(s[ck][0] - C);
                    float p1 = __builtin_amdgcn_exp2f(s[ck][1] - C);
                    float p2 = __builtin_amdgcn_exp2f(s[ck][2] - C);
                    float p3 = __builtin_amdgcn_exp2f(s[ck][3] - C);
                    pk[ck][0] = pk2(p0, p1);
                    pk[ck][1] = pk2(p2, p3);
                }
#pragma unroll
                for (int kc2 = 0; kc2 < 2; ++kc2) {
                    u32x4 w;
                    w.x = pk[kc2 * 2][0];
                    w.y = pk[kc2 * 2][1];
                    w.z = pk[kc2 * 2 + 1][0];
                    w.w = pk[kc2 * 2 + 1][1];
                    pa[mf][kc2] = __builtin_bit_cast(bf16x8, w);
                }
            }
            // PV + l-sum
#pragma unroll
            for (int hc = 0; hc < 4; ++hc) {
                bf16x8 v0 = *(const bf16x8*)(vbuf + (hc * 2 + 0) * 1024 + lane * 16);
                bf16x8 v1 = *(const bf16x8*)(vbuf + (hc * 2 + 1) * 1024 + lane * 16);
#pragma unroll
                for (int mf = 0; mf < 4; ++mf) {
                    o[mf][hc] = mfma16(pa[mf][0], v0, o[mf][hc]);
                    o[mf][hc] = mfma16(pa[mf][1], v1, o[mf][hc]);
                }
            }
#pragma unroll
            for (int mf = 0; mf < 4; ++mf) {
                lacc[mf] = mfma16(pa[mf][0], bones, lacc[mf]);
                lacc[mf] = mfma16(pa[mf][1], bones, lacc[mf]);
            }
            __builtin_amdgcn_s_setprio(0);
        }
        __syncthreads();
        cur ^= 1;
    }

    // epilogue
#pragma unroll
    for (int mf = 0; mf < 4; ++mf)
#pragma unroll
        for (int hc = 0; hc < 4; ++hc)
#pragma unroll
            for (int r = 0; r < 4; ++r) {
                int qrow = q0w + mf * 16 + lb * 4 + r;
                O[(size_t)(rowbase + qrow) * 1024 + colbase + hc * 16 + la] =
                    (bf16)(o[mf][hc][r] / lacc[mf][r]);
            }
}

// ---------------- launch ----------------
extern "C" void kernel_launch(void* const* d_in, const int* in_sizes, int n_in,
                              void* d_out, int out_size, void* d_ws, size_t ws_size,
                              hipStream_t stream) {
    const float* x  = (const float*)d_in[0];
    const float* Wq = (const float*)d_in[1];
    const float* Wk = (const float*)d_in[2];
    const float* Wv = (const float*)d_in[3];
    const float* Wo = (const float*)d_in[4];
    const float* bo = (const float*)d_in[5];
    float* out = (float*)d_out;

    char* ws = (char*)d_ws;
    const size_t MB = 1024 * 1024;
    bf16* xb  = (bf16*)(ws + (size_t)0);
    bf16* wqb = (bf16*)(ws + 8 * MB);
    bf16* wkb = (bf16*)(ws + 10 * MB);
    bf16* wvb = (bf16*)(ws + 12 * MB);
    bf16* wob = (bf16*)(ws + 14 * MB);
    bf16* Qb  = (bf16*)(ws + 16 * MB);
    bf16* Kf  = (bf16*)(ws + 24 * MB);   // 16 MB
    bf16* Vf  = (bf16*)(ws + 40 * MB);   // 16 MB
    bf16* Ab  = (bf16*)(ws + 56 * MB);

    conv_kernel<<<8192, 256, 0, stream>>>(x, Wq, Wk, Wv, Wo, xb, wqb, wkb, wvb, wob);

    gemm_qkv_kernel<<<dim3(32, 8, 3), 256, 0, stream>>>(xb, wqb, wkb, wvb, Qb, Kf, Vf);
    attn_kernel<<<256, 256, 0, stream>>>(Qb, Kf, Vf, Ab);
    gemm_out_kernel<<<dim3(32, 8), 256, 0, stream>>>(Ab, wob, out, bo);
}

// Round 16
// 131.123 us; speedup vs baseline: 1.0036x; 1.0036x over previous
//
#include <hip/hip_runtime.h>
#include <hip/hip_bf16.h>

// ParallelMHA: B=2, N=2048, D=1024, H=16, HD=64. fp32 in/out, bf16 MFMA compute.
// Pipeline: convert (1 launch) -> QKV GEMM (2-phase dbuf gload_lds; Q*log2e/8;
//           K,V fragment-direct) -> flash attn (R13: fixed-max, XCD-pinned,
//           swapped-QK, zero-shuffle P, biased-pointer prefetch) -> O GEMM
// R15 post-mortem: QBLK=64 halved waves to 1/SIMD + uniform-barrier idle =>
// 82us regression. Attn equilibrium is R13's 512x4 structure (41.6us) — reverted.
// R16: GEMM K-loop 2-phase double-buffer (T3-minimum, m248v2 +10%): stage(next)
// overlaps compute(cur), one barrier/K-step instead of two.

typedef __bf16 bf16;
typedef __bf16 bf16x2 __attribute__((ext_vector_type(2)));
typedef __bf16 bf16x4 __attribute__((ext_vector_type(4)));
typedef __bf16 bf16x8 __attribute__((ext_vector_type(8)));
typedef float f32x4 __attribute__((ext_vector_type(4)));
typedef unsigned int u32x4 __attribute__((ext_vector_type(4)));

__device__ __forceinline__ f32x4 mfma16(bf16x8 a, bf16x8 b, f32x4 c) {
    return __builtin_amdgcn_mfma_f32_16x16x32_bf16(a, b, c, 0, 0, 0);
}

__device__ __forceinline__ void gload16(const bf16* g, bf16* l) {
    __builtin_amdgcn_global_load_lds(
        (const __attribute__((address_space(1))) unsigned int*)g,
        (__attribute__((address_space(3))) unsigned int*)l, 16, 0, 0);
}

__device__ __forceinline__ unsigned pk2(float a, float b) {
    bf16x2 v;
    v[0] = (bf16)a;
    v[1] = (bf16)b;
    return __builtin_bit_cast(unsigned, v);
}

// ---------------- fp32 -> bf16 convert (x + 4 weights, one launch) ----------------
__global__ __launch_bounds__(256) void conv_kernel(
    const float* __restrict__ x, const float* __restrict__ w0,
    const float* __restrict__ w1, const float* __restrict__ w2,
    const float* __restrict__ w3, bf16* __restrict__ xb,
    bf16* __restrict__ o0, bf16* __restrict__ o1,
    bf16* __restrict__ o2, bf16* __restrict__ o3) {
    int blk = blockIdx.x;
    const float* in;
    bf16* out;
    int base;
    if (blk < 4096) {
        in = x; out = xb; base = blk;
    } else {
        int sel = (blk - 4096) >> 10;
        in = sel == 0 ? w0 : sel == 1 ? w1 : sel == 2 ? w2 : w3;
        out = sel == 0 ? o0 : sel == 1 ? o1 : sel == 2 ? o2 : o3;
        base = (blk - 4096) & 1023;
    }
    int i = (base * 256 + threadIdx.x) * 4;
    float4 v = *(const float4*)&in[i];
    bf16x4 o;
    o.x = (bf16)v.x; o.y = (bf16)v.y; o.z = (bf16)v.z; o.w = (bf16)v.w;
    *(bf16x4*)&out[i] = o;
}

// ---------------- 128x128 bf16 GEMM, 2-phase dbuf global_load_lds staging -------
// MODE 0: bf16 row-major *scale. MODE 1: f32 out + bias.
// MODE 2: V fragment-direct tiled (key-permuted). MODE 3: K fragment-direct tiled.
// Fragment-direct block (R13 layout): per (ktile,h) 4096 elems; (key,hd) at
//   K: ((key>>4)*2 + (hd>>5))*512 + (key&15)*32 + ((hd>>3)&3)*8 + (hd&7)
//   V: ((hd>>4)*2 + ((key>>4)>>1))*512 + (hd&15)*32 + ((key&15)>>2)*8 + ((key>>4)&1)*4 + (key&3)
template <int MODE>
__device__ __forceinline__ void gemm_body(const bf16* __restrict__ A,
                                          const bf16* __restrict__ B,
                                          bf16* __restrict__ Cb,
                                          float* __restrict__ Cf,
                                          const float* __restrict__ bias,
                                          float scale, int N, int K, int row0, int col0) {
    __shared__ alignas(16) bf16 sA[2][128 * 32];
    __shared__ alignas(16) bf16 sB[2][128 * 32];
    const int tid  = threadIdx.x;
    const int lane = tid & 63;
    const int wave = tid >> 6;
    const int wrow = (wave >> 1) * 64;
    const int wcol = (wave & 1) * 64;
    const int la = lane & 15, lb = lane >> 4;

    const f32x4 fzero = {0.f, 0.f, 0.f, 0.f};
    f32x4 acc[4][4];
#pragma unroll
    for (int m = 0; m < 4; ++m)
#pragma unroll
        for (int n = 0; n < 4; ++n) acc[m][n] = fzero;

    auto STAGE = [&](int k0, int buf) {
#pragma unroll
        for (int i = 0; i < 2; ++i) {
            int idx = i * 256 + tid;
            int r = idx >> 2, s = idx & 3;
            gload16(&A[(size_t)(row0 + r) * K + k0 + s * 8], &sA[buf][idx * 8]);
            gload16(&B[(size_t)(col0 + r) * K + k0 + s * 8], &sB[buf][idx * 8]);
        }
    };
    auto COMPUTE = [&](int buf) {
        bf16x8 af[4], bfv[4];
#pragma unroll
        for (int m = 0; m < 4; ++m)
            af[m] = *(const bf16x8*)&sA[buf][(wrow + m * 16 + la) * 32 + lb * 8];
#pragma unroll
        for (int n = 0; n < 4; ++n)
            bfv[n] = *(const bf16x8*)&sB[buf][(wcol + n * 16 + la) * 32 + lb * 8];
#pragma unroll
        for (int m = 0; m < 4; ++m)
#pragma unroll
            for (int n = 0; n < 4; ++n)
                acc[m][n] = mfma16(af[m], bfv[n], acc[m][n]);
    };

    STAGE(0, 0);
    __syncthreads();
    for (int k0 = 0; k0 < K; k0 += 64) {
        if (k0 + 32 < K) STAGE(k0 + 32, 1);
        COMPUTE(0);
        __syncthreads();
        if (k0 + 64 < K) STAGE(k0 + 64, 0);
        COMPUTE(1);
        __syncthreads();
    }
#pragma unroll
    for (int m = 0; m < 4; ++m)
#pragma unroll
        for (int n = 0; n < 4; ++n) {
            int col = col0 + wcol + n * 16 + la;
            if (MODE == 2) {
                int hh = col >> 6, hd = col & 63;
                int hc = hd >> 4, lav = hd & 15;
                int sp = row0 + wrow + m * 16 + lb * 4;
                int ktile = sp >> 6, k = sp & 63;
                int c = k >> 4, q = k & 15;
                size_t addr = (size_t)(ktile * 16 + hh) * 4096 +
                              (size_t)(((hc * 2 + (c >> 1)) * 16 + lav) * 32 +
                                       (q >> 2) * 8 + (c & 1) * 4);
                bf16x4 o4;
#pragma unroll
                for (int r = 0; r < 4; ++r) o4[r] = (bf16)acc[m][n][r];
                *(bf16x4*)&Cb[addr] = o4;
            } else if (MODE == 3) {
                int hh = col >> 6, hd = col & 63;
#pragma unroll
                for (int r = 0; r < 4; ++r) {
                    int row = row0 + wrow + m * 16 + lb * 4 + r;
                    int ktile = row >> 6, key = row & 63;
                    size_t addr = (size_t)(ktile * 16 + hh) * 4096 +
                                  (size_t)((((key >> 4) * 2 + (hd >> 5)) * 16 +
                                            (key & 15)) * 32 +
                                           ((hd >> 3) & 3) * 8 + (hd & 7));
                    Cb[addr] = (bf16)acc[m][n][r];
                }
            } else {
#pragma unroll
                for (int r = 0; r < 4; ++r) {
                    int row = row0 + wrow + m * 16 + lb * 4 + r;
                    if (MODE == 1)
                        Cf[(size_t)row * N + col] = acc[m][n][r] + bias[col];
                    else
                        Cb[(size_t)row * N + col] = (bf16)(acc[m][n][r] * scale);
                }
            }
        }
}

__global__ __launch_bounds__(256) void gemm_qkv_kernel(
    const bf16* __restrict__ xb, const bf16* __restrict__ wq,
    const bf16* __restrict__ wk, const bf16* __restrict__ wv,
    bf16* __restrict__ Q, bf16* __restrict__ Kf, bf16* __restrict__ Vf) {
    int z = blockIdx.z;
    if (z == 2) {
        gemm_body<2>(xb, wv, Vf, nullptr, nullptr, 1.f, 1024, 1024,
                     blockIdx.x * 128, blockIdx.y * 128);
    } else if (z == 1) {
        gemm_body<3>(xb, wk, Kf, nullptr, nullptr, 1.f, 1024, 1024,
                     blockIdx.x * 128, blockIdx.y * 128);
    } else {
        gemm_body<0>(xb, wq, Q, nullptr, nullptr, 0.1803368801111204f, 1024, 1024,
                     blockIdx.x * 128, blockIdx.y * 128);
    }
}

__global__ __launch_bounds__(256) void gemm_out_kernel(
    const bf16* __restrict__ att, const bf16* __restrict__ wo,
    float* __restrict__ out, const float* __restrict__ bias) {
    gemm_body<1>(att, wo, nullptr, out, bias, 1.f, 1024, 1024,
                 blockIdx.x * 128, blockIdx.y * 128);
}

// ---------------- flash attention: R13 structure (verbatim revert) ----------------
// Q/O: [b*2048+n][h*64+hd] (ld 1024). Kf/Vf: fragment-direct (ktile,h) 8KB blocks.
// 512 blocks x 4 waves, 32 q-rows/wave, KBLK=64. p = exp2(s - 10*log2e) fixed-max.
// Loop-carried biased pointers; K and V prefetched one tile ahead; setprio.
struct KF { bf16x8 f[4][2]; };

__global__ __launch_bounds__(256, 2) void attn_kernel(
    const bf16* __restrict__ Q, const bf16* __restrict__ Kf,
    const bf16* __restrict__ Vf, bf16* __restrict__ O) {
    const int lane = threadIdx.x & 63;
    const int wave = threadIdx.x >> 6;
    const int bid = blockIdx.x;                       // 0..511
    const int bh = (bid & 7) * 4 + ((bid >> 3) & 3);  // XCD-pinned (b,h)
    const int slot = bid >> 5;                        // 0..15
    const int qt = slot < 8 ? slot : 23 - slot;       // long+short pairing
    const int h = bh & 15;
    const int b = bh >> 4;
    const int q0w = qt * 128 + wave * 32;
    const int rowbase = b * 2048;
    const int la = lane & 15, lb = lane >> 4;
    const f32x4 fzero = {0.f, 0.f, 0.f, 0.f};
    const float C = 14.426950408889634f;  // 10 * log2(e)
    const int colbase = h * 64;
    const int lane_off = la * 32 + lb * 8;
    const int TSTRIDE = 16 * 4096;        // elements between consecutive ktiles

    bf16x8 aq[2][2];
#pragma unroll
    for (int mf = 0; mf < 2; ++mf) {
        const bf16* qp = &Q[(size_t)(rowbase + q0w + mf * 16 + la) * 1024 + colbase];
#pragma unroll
        for (int kc = 0; kc < 2; ++kc) aq[mf][kc] = *(const bf16x8*)(qp + kc * 32 + lb * 8);
    }

    bf16x8 bones;
#pragma unroll
    for (int j = 0; j < 8; ++j) bones[j] = (bf16)1.0f;

    f32x4 o[2][4], lacc[2];
#pragma unroll
    for (int mf = 0; mf < 2; ++mf) {
        lacc[mf] = fzero;
#pragma unroll
        for (int hc = 0; hc < 4; ++hc) o[mf][hc] = fzero;
    }

    const int nt = (q0w + 95) >> 6;  // exact causal trip count

    const bf16* kbase = &Kf[(size_t)(b * 32 * 16 + h) * 4096 + lane_off + 2048];
    const bf16* vbase = &Vf[(size_t)(b * 32 * 16 + h) * 4096 + lane_off + 2048];

    KF ka, kb, va, vb;
#pragma unroll
    for (int ck = 0; ck < 4; ++ck) {  // tile 0 K+V -> ka/va
        ka.f[ck][0] = *(const bf16x8*)(kbase + (ck * 2 + 0) * 512 - 2048);
        ka.f[ck][1] = *(const bf16x8*)(kbase + (ck * 2 + 1) * 512 - 2048);
        va.f[ck][0] = *(const bf16x8*)(vbase + (ck * 2 + 0) * 512 - 2048);
        va.f[ck][1] = *(const bf16x8*)(vbase + (ck * 2 + 1) * 512 - 2048);
    }
    const bf16* kpf = kbase + (nt > 1 ? TSTRIDE : 0);
    const bf16* vpf = vbase + (nt > 1 ? TSTRIDE : 0);

    auto TILE = [&](int t, KF& kc, KF& kn, KF& vc, KF& vn) {
        const bool domask = (t == nt - 1);
#pragma unroll
        for (int ck = 0; ck < 4; ++ck) {
            kn.f[ck][0] = *(const bf16x8*)(kpf + (ck * 2 + 0) * 512 - 2048);
            kn.f[ck][1] = *(const bf16x8*)(kpf + (ck * 2 + 1) * 512 - 2048);
            vn.f[ck][0] = *(const bf16x8*)(vpf + (ck * 2 + 0) * 512 - 2048);
            vn.f[ck][1] = *(const bf16x8*)(vpf + (ck * 2 + 1) * 512 - 2048);
        }
        int adv = (t + 2 < nt) ? TSTRIDE : 0;
        kpf += adv;
        vpf += adv;
        f32x4 s[2][4];
#pragma unroll
        for (int mf = 0; mf < 2; ++mf)
#pragma unroll
            for (int ck = 0; ck < 4; ++ck) s[mf][ck] = fzero;
        __builtin_amdgcn_s_setprio(1);
#pragma unroll
        for (int ck = 0; ck < 4; ++ck)
#pragma unroll
            for (int mf = 0; mf < 2; ++mf) {
                s[mf][ck] = mfma16(kc.f[ck][0], aq[mf][0], s[mf][ck]);
                s[mf][ck] = mfma16(kc.f[ck][1], aq[mf][1], s[mf][ck]);
            }
        __builtin_amdgcn_s_setprio(0);
        if (domask) {
            const int k0 = t * 64;
#pragma unroll
            for (int mf = 0; mf < 2; ++mf) {
                int qrow = q0w + mf * 16 + la;
#pragma unroll
                for (int ck = 0; ck < 4; ++ck)
#pragma unroll
                    for (int r = 0; r < 4; ++r) {
                        int key = k0 + ck * 16 + lb * 4 + r;
                        if (key > qrow) s[mf][ck][r] = -1e30f;
                    }
            }
        }
        bf16x8 pa[2][2];
#pragma unroll
        for (int mf = 0; mf < 2; ++mf) {
            unsigned pk[4][2];
#pragma unroll
            for (int ck = 0; ck < 4; ++ck) {
                float p0 = __builtin_amdgcn_exp2f(s[mf][ck][0] - C);
                float p1 = __builtin_amdgcn_exp2f(s[mf][ck][1] - C);
                float p2 = __builtin_amdgcn_exp2f(s[mf][ck][2] - C);
                float p3 = __builtin_amdgcn_exp2f(s[mf][ck][3] - C);
                pk[ck][0] = pk2(p0, p1);
                pk[ck][1] = pk2(p2, p3);
            }
#pragma unroll
            for (int kc2 = 0; kc2 < 2; ++kc2) {
                u32x4 w;
                w.x = pk[kc2 * 2][0];
                w.y = pk[kc2 * 2][1];
                w.z = pk[kc2 * 2 + 1][0];
                w.w = pk[kc2 * 2 + 1][1];
                pa[mf][kc2] = __builtin_bit_cast(bf16x8, w);
            }
        }
        __builtin_amdgcn_s_setprio(1);
#pragma unroll
        for (int hc = 0; hc < 4; ++hc)
#pragma unroll
            for (int mf = 0; mf < 2; ++mf) {
                o[mf][hc] = mfma16(pa[mf][0], vc.f[hc][0], o[mf][hc]);
                o[mf][hc] = mfma16(pa[mf][1], vc.f[hc][1], o[mf][hc]);
            }
#pragma unroll
        for (int mf = 0; mf < 2; ++mf) {
            lacc[mf] = mfma16(pa[mf][0], bones, lacc[mf]);
            lacc[mf] = mfma16(pa[mf][1], bones, lacc[mf]);
        }
        __builtin_amdgcn_s_setprio(0);
    };

    int t = 0;
    for (; t + 2 <= nt; t += 2) {
        TILE(t, ka, kb, va, vb);
        TILE(t + 1, kb, ka, vb, va);
    }
    if (t < nt) TILE(t, ka, kb, va, vb);

    // epilogue
#pragma unroll
    for (int mf = 0; mf < 2; ++mf)
#pragma unroll
        for (int hc = 0; hc < 4; ++hc)
#pragma unroll
            for (int r = 0; r < 4; ++r) {
                int qrow = q0w + mf * 16 + lb * 4 + r;
                O[(size_t)(rowbase + qrow) * 1024 + colbase + hc * 16 + la] =
                    (bf16)(o[mf][hc][r] / lacc[mf][r]);
            }
}

// ---------------- launch ----------------
extern "C" void kernel_launch(void* const* d_in, const int* in_sizes, int n_in,
                              void* d_out, int out_size, void* d_ws, size_t ws_size,
                              hipStream_t stream) {
    const float* x  = (const float*)d_in[0];
    const float* Wq = (const float*)d_in[1];
    const float* Wk = (const float*)d_in[2];
    const float* Wv = (const float*)d_in[3];
    const float* Wo = (const float*)d_in[4];
    const float* bo = (const float*)d_in[5];
    float* out = (float*)d_out;

    char* ws = (char*)d_ws;
    const size_t MB = 1024 * 1024;
    bf16* xb  = (bf16*)(ws + (size_t)0);
    bf16* wqb = (bf16*)(ws + 8 * MB);
    bf16* wkb = (bf16*)(ws + 10 * MB);
    bf16* wvb = (bf16*)(ws + 12 * MB);
    bf16* wob = (bf16*)(ws + 14 * MB);
    bf16* Qb  = (bf16*)(ws + 16 * MB);
    bf16* Kf  = (bf16*)(ws + 24 * MB);   // 16 MB
    bf16* Vf  = (bf16*)(ws + 40 * MB);   // 16 MB
    bf16* Ab  = (bf16*)(ws + 56 * MB);

    conv_kernel<<<8192, 256, 0, stream>>>(x, Wq, Wk, Wv, Wo, xb, wqb, wkb, wvb, wob);

    gemm_qkv_kernel<<<dim3(32, 8, 3), 256, 0, stream>>>(xb, wqb, wkb, wvb, Qb, Kf, Vf);
    attn_kernel<<<512, 256, 0, stream>>>(Qb, Kf, Vf, Ab);
    gemm_out_kernel<<<dim3(32, 8), 256, 0, stream>>>(Ab, wob, out, bo);
}

// Round 17
// 100.226 us; speedup vs baseline: 1.3130x; 1.3083x over previous
//
#include <hip/hip_runtime.h>
#include <hip/hip_bf16.h>

// ParallelMHA: B=2, N=2048, D=1024, H=16, HD=64. fp32 in/out, bf16 MFMA compute.
// Pipeline: convert (1 launch) -> QKV GEMM (2-phase dbuf, DYNAMIC shared LDS;
//           Q*log2e/8; K,V fragment-direct) -> flash attn (R13 structure) -> O GEMM
// R16 post-mortem: per-instantiation static __shared__ inside gemm_body x3 MODEs
// = 96KB/block => 1 block/CU => QKV GEMM 84us @ 11% occupancy. R17: one dynamic
// 32KB LDS allocation shared by all instantiations (5 blocks/CU), dbuf kept.

typedef __bf16 bf16;
typedef __bf16 bf16x2 __attribute__((ext_vector_type(2)));
typedef __bf16 bf16x4 __attribute__((ext_vector_type(4)));
typedef __bf16 bf16x8 __attribute__((ext_vector_type(8)));
typedef float f32x4 __attribute__((ext_vector_type(4)));
typedef unsigned int u32x4 __attribute__((ext_vector_type(4)));

__device__ __forceinline__ f32x4 mfma16(bf16x8 a, bf16x8 b, f32x4 c) {
    return __builtin_amdgcn_mfma_f32_16x16x32_bf16(a, b, c, 0, 0, 0);
}

__device__ __forceinline__ void gload16(const bf16* g, bf16* l) {
    __builtin_amdgcn_global_load_lds(
        (const __attribute__((address_space(1))) unsigned int*)g,
        (__attribute__((address_space(3))) unsigned int*)l, 16, 0, 0);
}

__device__ __forceinline__ unsigned pk2(float a, float b) {
    bf16x2 v;
    v[0] = (bf16)a;
    v[1] = (bf16)b;
    return __builtin_bit_cast(unsigned, v);
}

// ---------------- fp32 -> bf16 convert (x + 4 weights, one launch) ----------------
__global__ __launch_bounds__(256) void conv_kernel(
    const float* __restrict__ x, const float* __restrict__ w0,
    const float* __restrict__ w1, const float* __restrict__ w2,
    const float* __restrict__ w3, bf16* __restrict__ xb,
    bf16* __restrict__ o0, bf16* __restrict__ o1,
    bf16* __restrict__ o2, bf16* __restrict__ o3) {
    int blk = blockIdx.x;
    const float* in;
    bf16* out;
    int base;
    if (blk < 4096) {
        in = x; out = xb; base = blk;
    } else {
        int sel = (blk - 4096) >> 10;
        in = sel == 0 ? w0 : sel == 1 ? w1 : sel == 2 ? w2 : w3;
        out = sel == 0 ? o0 : sel == 1 ? o1 : sel == 2 ? o2 : o3;
        base = (blk - 4096) & 1023;
    }
    int i = (base * 256 + threadIdx.x) * 4;
    float4 v = *(const float4*)&in[i];
    bf16x4 o;
    o.x = (bf16)v.x; o.y = (bf16)v.y; o.z = (bf16)v.z; o.w = (bf16)v.w;
    *(bf16x4*)&out[i] = o;
}

// ---------------- 128x128 bf16 GEMM, 2-phase dbuf, dynamic LDS -------
// sA/sB: [2][128*32] bf16 each (16KB + 16KB dynamic).
// MODE 0: bf16 row-major *scale. MODE 1: f32 out + bias.
// MODE 2: V fragment-direct tiled (key-permuted). MODE 3: K fragment-direct tiled.
template <int MODE>
__device__ __forceinline__ void gemm_body(bf16* __restrict__ sA, bf16* __restrict__ sB,
                                          const bf16* __restrict__ A,
                                          const bf16* __restrict__ B,
                                          bf16* __restrict__ Cb,
                                          float* __restrict__ Cf,
                                          const float* __restrict__ bias,
                                          float scale, int N, int K, int row0, int col0) {
    const int tid  = threadIdx.x;
    const int lane = tid & 63;
    const int wave = tid >> 6;
    const int wrow = (wave >> 1) * 64;
    const int wcol = (wave & 1) * 64;
    const int la = lane & 15, lb = lane >> 4;

    const f32x4 fzero = {0.f, 0.f, 0.f, 0.f};
    f32x4 acc[4][4];
#pragma unroll
    for (int m = 0; m < 4; ++m)
#pragma unroll
        for (int n = 0; n < 4; ++n) acc[m][n] = fzero;

    auto STAGE = [&](int k0, int buf) {
#pragma unroll
        for (int i = 0; i < 2; ++i) {
            int idx = i * 256 + tid;
            int r = idx >> 2, s = idx & 3;
            gload16(&A[(size_t)(row0 + r) * K + k0 + s * 8], &sA[buf * 4096 + idx * 8]);
            gload16(&B[(size_t)(col0 + r) * K + k0 + s * 8], &sB[buf * 4096 + idx * 8]);
        }
    };
    auto COMPUTE = [&](int buf) {
        bf16x8 af[4], bfv[4];
#pragma unroll
        for (int m = 0; m < 4; ++m)
            af[m] = *(const bf16x8*)&sA[buf * 4096 + (wrow + m * 16 + la) * 32 + lb * 8];
#pragma unroll
        for (int n = 0; n < 4; ++n)
            bfv[n] = *(const bf16x8*)&sB[buf * 4096 + (wcol + n * 16 + la) * 32 + lb * 8];
#pragma unroll
        for (int m = 0; m < 4; ++m)
#pragma unroll
            for (int n = 0; n < 4; ++n)
                acc[m][n] = mfma16(af[m], bfv[n], acc[m][n]);
    };

    STAGE(0, 0);
    __syncthreads();
    for (int k0 = 0; k0 < K; k0 += 64) {
        if (k0 + 32 < K) STAGE(k0 + 32, 1);
        COMPUTE(0);
        __syncthreads();
        if (k0 + 64 < K) STAGE(k0 + 64, 0);
        COMPUTE(1);
        __syncthreads();
    }
#pragma unroll
    for (int m = 0; m < 4; ++m)
#pragma unroll
        for (int n = 0; n < 4; ++n) {
            int col = col0 + wcol + n * 16 + la;
            if (MODE == 2) {
                int hh = col >> 6, hd = col & 63;
                int hc = hd >> 4, lav = hd & 15;
                int sp = row0 + wrow + m * 16 + lb * 4;
                int ktile = sp >> 6, k = sp & 63;
                int c = k >> 4, q = k & 15;
                size_t addr = (size_t)(ktile * 16 + hh) * 4096 +
                              (size_t)(((hc * 2 + (c >> 1)) * 16 + lav) * 32 +
                                       (q >> 2) * 8 + (c & 1) * 4);
                bf16x4 o4;
#pragma unroll
                for (int r = 0; r < 4; ++r) o4[r] = (bf16)acc[m][n][r];
                *(bf16x4*)&Cb[addr] = o4;
            } else if (MODE == 3) {
                int hh = col >> 6, hd = col & 63;
#pragma unroll
                for (int r = 0; r < 4; ++r) {
                    int row = row0 + wrow + m * 16 + lb * 4 + r;
                    int ktile = row >> 6, key = row & 63;
                    size_t addr = (size_t)(ktile * 16 + hh) * 4096 +
                                  (size_t)((((key >> 4) * 2 + (hd >> 5)) * 16 +
                                            (key & 15)) * 32 +
                                           ((hd >> 3) & 3) * 8 + (hd & 7));
                    Cb[addr] = (bf16)acc[m][n][r];
                }
            } else {
#pragma unroll
                for (int r = 0; r < 4; ++r) {
                    int row = row0 + wrow + m * 16 + lb * 4 + r;
                    if (MODE == 1)
                        Cf[(size_t)row * N + col] = acc[m][n][r] + bias[col];
                    else
                        Cb[(size_t)row * N + col] = (bf16)(acc[m][n][r] * scale);
                }
            }
        }
}

__global__ __launch_bounds__(256) void gemm_qkv_kernel(
    const bf16* __restrict__ xb, const bf16* __restrict__ wq,
    const bf16* __restrict__ wk, const bf16* __restrict__ wv,
    bf16* __restrict__ Q, bf16* __restrict__ Kf, bf16* __restrict__ Vf) {
    extern __shared__ char dyn[];
    bf16* sA = (bf16*)dyn;              // [2][4096]
    bf16* sB = (bf16*)(dyn + 16384);    // [2][4096]
    int z = blockIdx.z;
    if (z == 2) {
        gemm_body<2>(sA, sB, xb, wv, Vf, nullptr, nullptr, 1.f, 1024, 1024,
                     blockIdx.x * 128, blockIdx.y * 128);
    } else if (z == 1) {
        gemm_body<3>(sA, sB, xb, wk, Kf, nullptr, nullptr, 1.f, 1024, 1024,
                     blockIdx.x * 128, blockIdx.y * 128);
    } else {
        gemm_body<0>(sA, sB, xb, wq, Q, nullptr, nullptr, 0.1803368801111204f,
                     1024, 1024, blockIdx.x * 128, blockIdx.y * 128);
    }
}

__global__ __launch_bounds__(256) void gemm_out_kernel(
    const bf16* __restrict__ att, const bf16* __restrict__ wo,
    float* __restrict__ out, const float* __restrict__ bias) {
    extern __shared__ char dyn[];
    bf16* sA = (bf16*)dyn;
    bf16* sB = (bf16*)(dyn + 16384);
    gemm_body<1>(sA, sB, att, wo, nullptr, out, bias, 1.f, 1024, 1024,
                 blockIdx.x * 128, blockIdx.y * 128);
}

// ---------------- flash attention: R13 structure (unchanged) ----------------
// Q/O: [b*2048+n][h*64+hd] (ld 1024). Kf/Vf: fragment-direct (ktile,h) 8KB blocks.
// 512 blocks x 4 waves, 32 q-rows/wave, KBLK=64. p = exp2(s - 10*log2e) fixed-max.
struct KF { bf16x8 f[4][2]; };

__global__ __launch_bounds__(256, 2) void attn_kernel(
    const bf16* __restrict__ Q, const bf16* __restrict__ Kf,
    const bf16* __restrict__ Vf, bf16* __restrict__ O) {
    const int lane = threadIdx.x & 63;
    const int wave = threadIdx.x >> 6;
    const int bid = blockIdx.x;                       // 0..511
    const int bh = (bid & 7) * 4 + ((bid >> 3) & 3);  // XCD-pinned (b,h)
    const int slot = bid >> 5;                        // 0..15
    const int qt = slot < 8 ? slot : 23 - slot;       // long+short pairing
    const int h = bh & 15;
    const int b = bh >> 4;
    const int q0w = qt * 128 + wave * 32;
    const int rowbase = b * 2048;
    const int la = lane & 15, lb = lane >> 4;
    const f32x4 fzero = {0.f, 0.f, 0.f, 0.f};
    const float C = 14.426950408889634f;  // 10 * log2(e)
    const int colbase = h * 64;
    const int lane_off = la * 32 + lb * 8;
    const int TSTRIDE = 16 * 4096;

    bf16x8 aq[2][2];
#pragma unroll
    for (int mf = 0; mf < 2; ++mf) {
        const bf16* qp = &Q[(size_t)(rowbase + q0w + mf * 16 + la) * 1024 + colbase];
#pragma unroll
        for (int kc = 0; kc < 2; ++kc) aq[mf][kc] = *(const bf16x8*)(qp + kc * 32 + lb * 8);
    }

    bf16x8 bones;
#pragma unroll
    for (int j = 0; j < 8; ++j) bones[j] = (bf16)1.0f;

    f32x4 o[2][4], lacc[2];
#pragma unroll
    for (int mf = 0; mf < 2; ++mf) {
        lacc[mf] = fzero;
#pragma unroll
        for (int hc = 0; hc < 4; ++hc) o[mf][hc] = fzero;
    }

    const int nt = (q0w + 95) >> 6;  // exact causal trip count

    const bf16* kbase = &Kf[(size_t)(b * 32 * 16 + h) * 4096 + lane_off + 2048];
    const bf16* vbase = &Vf[(size_t)(b * 32 * 16 + h) * 4096 + lane_off + 2048];

    KF ka, kb, va, vb;
#pragma unroll
    for (int ck = 0; ck < 4; ++ck) {
        ka.f[ck][0] = *(const bf16x8*)(kbase + (ck * 2 + 0) * 512 - 2048);
        ka.f[ck][1] = *(const bf16x8*)(kbase + (ck * 2 + 1) * 512 - 2048);
        va.f[ck][0] = *(const bf16x8*)(vbase + (ck * 2 + 0) * 512 - 2048);
        va.f[ck][1] = *(const bf16x8*)(vbase + (ck * 2 + 1) * 512 - 2048);
    }
    const bf16* kpf = kbase + (nt > 1 ? TSTRIDE : 0);
    const bf16* vpf = vbase + (nt > 1 ? TSTRIDE : 0);

    auto TILE = [&](int t, KF& kc, KF& kn, KF& vc, KF& vn) {
        const bool domask = (t == nt - 1);
#pragma unroll
        for (int ck = 0; ck < 4; ++ck) {
            kn.f[ck][0] = *(const bf16x8*)(kpf + (ck * 2 + 0) * 512 - 2048);
            kn.f[ck][1] = *(const bf16x8*)(kpf + (ck * 2 + 1) * 512 - 2048);
            vn.f[ck][0] = *(const bf16x8*)(vpf + (ck * 2 + 0) * 512 - 2048);
            vn.f[ck][1] = *(const bf16x8*)(vpf + (ck * 2 + 1) * 512 - 2048);
        }
        int adv = (t + 2 < nt) ? TSTRIDE : 0;
        kpf += adv;
        vpf += adv;
        f32x4 s[2][4];
#pragma unroll
        for (int mf = 0; mf < 2; ++mf)
#pragma unroll
            for (int ck = 0; ck < 4; ++ck) s[mf][ck] = fzero;
        __builtin_amdgcn_s_setprio(1);
#pragma unroll
        for (int ck = 0; ck < 4; ++ck)
#pragma unroll
            for (int mf = 0; mf < 2; ++mf) {
                s[mf][ck] = mfma16(kc.f[ck][0], aq[mf][0], s[mf][ck]);
                s[mf][ck] = mfma16(kc.f[ck][1], aq[mf][1], s[mf][ck]);
            }
        __builtin_amdgcn_s_setprio(0);
        if (domask) {
            const int k0 = t * 64;
#pragma unroll
            for (int mf = 0; mf < 2; ++mf) {
                int qrow = q0w + mf * 16 + la;
#pragma unroll
                for (int ck = 0; ck < 4; ++ck)
#pragma unroll
                    for (int r = 0; r < 4; ++r) {
                        int key = k0 + ck * 16 + lb * 4 + r;
                        if (key > qrow) s[mf][ck][r] = -1e30f;
                    }
            }
        }
        bf16x8 pa[2][2];
#pragma unroll
        for (int mf = 0; mf < 2; ++mf) {
            unsigned pk[4][2];
#pragma unroll
            for (int ck = 0; ck < 4; ++ck) {
                float p0 = __builtin_amdgcn_exp2f(s[mf][ck][0] - C);
                float p1 = __builtin_amdgcn_exp2f(s[mf][ck][1] - C);
                float p2 = __builtin_amdgcn_exp2f(s[mf][ck][2] - C);
                float p3 = __builtin_amdgcn_exp2f(s[mf][ck][3] - C);
                pk[ck][0] = pk2(p0, p1);
                pk[ck][1] = pk2(p2, p3);
            }
#pragma unroll
            for (int kc2 = 0; kc2 < 2; ++kc2) {
                u32x4 w;
                w.x = pk[kc2 * 2][0];
                w.y = pk[kc2 * 2][1];
                w.z = pk[kc2 * 2 + 1][0];
                w.w = pk[kc2 * 2 + 1][1];
                pa[mf][kc2] = __builtin_bit_cast(bf16x8, w);
            }
        }
        __builtin_amdgcn_s_setprio(1);
#pragma unroll
        for (int hc = 0; hc < 4; ++hc)
#pragma unroll
            for (int mf = 0; mf < 2; ++mf) {
                o[mf][hc] = mfma16(pa[mf][0], vc.f[hc][0], o[mf][hc]);
                o[mf][hc] = mfma16(pa[mf][1], vc.f[hc][1], o[mf][hc]);
            }
#pragma unroll
        for (int mf = 0; mf < 2; ++mf) {
            lacc[mf] = mfma16(pa[mf][0], bones, lacc[mf]);
            lacc[mf] = mfma16(pa[mf][1], bones, lacc[mf]);
        }
        __builtin_amdgcn_s_setprio(0);
    };

    int t = 0;
    for (; t + 2 <= nt; t += 2) {
        TILE(t, ka, kb, va, vb);
        TILE(t + 1, kb, ka, vb, va);
    }
    if (t < nt) TILE(t, ka, kb, va, vb);

    // epilogue
#pragma unroll
    for (int mf = 0; mf < 2; ++mf)
#pragma unroll
        for (int hc = 0; hc < 4; ++hc)
#pragma unroll
            for (int r = 0; r < 4; ++r) {
                int qrow = q0w + mf * 16 + lb * 4 + r;
                O[(size_t)(rowbase + qrow) * 1024 + colbase + hc * 16 + la] =
                    (bf16)(o[mf][hc][r] / lacc[mf][r]);
            }
}

// ---------------- launch ----------------
extern "C" void kernel_launch(void* const* d_in, const int* in_sizes, int n_in,
                              void* d_out, int out_size, void* d_ws, size_t ws_size,
                              hipStream_t stream) {
    const float* x  = (const float*)d_in[0];
    const float* Wq = (const float*)d_in[1];
    const float* Wk = (const float*)d_in[2];
    const float* Wv = (const float*)d_in[3];
    const float* Wo = (const float*)d_in[4];
    const float* bo = (const float*)d_in[5];
    float* out = (float*)d_out;

    char* ws = (char*)d_ws;
    const size_t MB = 1024 * 1024;
    bf16* xb  = (bf16*)(ws + (size_t)0);
    bf16* wqb = (bf16*)(ws + 8 * MB);
    bf16* wkb = (bf16*)(ws + 10 * MB);
    bf16* wvb = (bf16*)(ws + 12 * MB);
    bf16* wob = (bf16*)(ws + 14 * MB);
    bf16* Qb  = (bf16*)(ws + 16 * MB);
    bf16* Kf  = (bf16*)(ws + 24 * MB);   // 16 MB
    bf16* Vf  = (bf16*)(ws + 40 * MB);   // 16 MB
    bf16* Ab  = (bf16*)(ws + 56 * MB);

    conv_kernel<<<8192, 256, 0, stream>>>(x, Wq, Wk, Wv, Wo, xb, wqb, wkb, wvb, wob);

    gemm_qkv_kernel<<<dim3(32, 8, 3), 256, 32768, stream>>>(xb, wqb, wkb, wvb,
                                                            Qb, Kf, Vf);
    attn_kernel<<<512, 256, 0, stream>>>(Qb, Kf, Vf, Ab);
    gemm_out_kernel<<<dim3(32, 8), 256, 32768, stream>>>(Ab, wob, out, bo);
}